// Round 15
// baseline (2218.365 us; speedup 1.0000x reference)
//
#include <hip/hip_runtime.h>
#include <stdint.h>

typedef unsigned short u16;
typedef unsigned int u32;
typedef unsigned long long u64;
typedef __attribute__((ext_vector_type(8))) short short8;   // 8 x bf16
typedef __attribute__((ext_vector_type(4))) float f32x4;
typedef __attribute__((ext_vector_type(4))) int int4v;

#define SEQ 256
#define GATE_WGS 64
#define D_WGS 8
#define NWG 73          // 64 gate + 8 d (feat-partial producers) + 1 lazy y
#define A_ELE 49152     // elements per A ring slot (bf16); feat section unused
#define D_ELE 16384
#define FACC_ELE 16384  // f32 per featacc slot (64 m x 256 c)

__device__ __forceinline__ u16 f2bf(float f) {
  u32 u = __float_as_uint(f);
  u += 0x7FFFu + ((u >> 16) & 1u);
  return (u16)(u >> 16);
}
__device__ __forceinline__ float bf2f(u16 v) {
  return __uint_as_float(((u32)v) << 16);
}
__device__ __forceinline__ short8 cvt8(const float* __restrict__ p) {
  short8 r;
#pragma unroll
  for (int j = 0; j < 8; ++j) r[j] = (short)f2bf(p[j]);
  return r;
}
__device__ __forceinline__ short8 cvt8v(const float* __restrict__ p) {  // 2x float4
  f32x4 a = *(const f32x4*)p, b = *(const f32x4*)(p + 4);
  short8 r;
#pragma unroll
  for (int j = 0; j < 4; ++j) { r[j] = (short)f2bf(a[j]); r[4 + j] = (short)f2bf(b[j]); }
  return r;
}
__device__ __forceinline__ float fast_tanh(float x) {
  return 1.0f - 2.0f / (1.0f + __expf(2.0f * x));
}
__device__ __forceinline__ float fast_sig(float x) {
  return 1.0f / (1.0f + __expf(-x));
}

union V16 { short8 s; u64 q[2]; };
// device-coherent load/store (bypass L1/L2 -> coherence point), fence-free
__device__ __forceinline__ short8 ldc16(const u16* p) {
  V16 v;
  v.q[0] = __hip_atomic_load((const u64*)p,     __ATOMIC_RELAXED, __HIP_MEMORY_SCOPE_AGENT);
  v.q[1] = __hip_atomic_load((const u64*)p + 1, __ATOMIC_RELAXED, __HIP_MEMORY_SCOPE_AGENT);
  return v.s;
}
__device__ __forceinline__ f32x4 ldc16f(const float* p) {
  union { f32x4 f; u64 q[2]; } v;
  v.q[0] = __hip_atomic_load((const u64*)p,     __ATOMIC_RELAXED, __HIP_MEMORY_SCOPE_AGENT);
  v.q[1] = __hip_atomic_load((const u64*)p + 1, __ATOMIC_RELAXED, __HIP_MEMORY_SCOPE_AGENT);
  return v.f;
}
__device__ __forceinline__ void stc16(u16* p, const u64* s) {
  __hip_atomic_store((u64*)p,     s[0], __ATOMIC_RELAXED, __HIP_MEMORY_SCOPE_AGENT);
  __hip_atomic_store((u64*)p + 1, s[1], __ATOMIC_RELAXED, __HIP_MEMORY_SCOPE_AGENT);
}
__device__ __forceinline__ void atadd(float* p, float v) {
  (void)__hip_atomic_fetch_add(p, v, __ATOMIC_RELAXED, __HIP_MEMORY_SCOPE_AGENT);
}
__device__ __forceinline__ void pollge(u32* p, u32 v) {
  while (__hip_atomic_load(p, __ATOMIC_RELAXED, __HIP_MEMORY_SCOPE_AGENT) < v) {}
}
__device__ __forceinline__ void setflag(u32* p, u32 v) {
  __hip_atomic_store(p, v, __ATOMIC_RELAXED, __HIP_MEMORY_SCOPE_AGENT);
}
// per-wave store drain: prior coherent stores reach coherence point before flag
#define VMCNT0() asm volatile("s_waitcnt vmcnt(0)" ::: "memory")

// ---------------------------------------------------------------------------
// prep_misc: zero h slot0 / flags / featacc; bcomb = W_fx@b_out + b_fx;
// Wcpack = bf16 MFMA-B-frag pack of Wcomb = W_fx @ W_out  [256 c][256 dec].
// ---------------------------------------------------------------------------
__global__ void prep_misc(const float* __restrict__ W_fx, const float* __restrict__ b_fx,
                          const float* __restrict__ W_out, const float* __restrict__ b_out,
                          u16* __restrict__ Abuf0, u32* __restrict__ flags,
                          float* __restrict__ featacc, float* __restrict__ bcomb,
                          u16* __restrict__ Wcpack) {
  int b = blockIdx.x, tid = threadIdx.x;
  if (b == 0) {
    for (int it = 0; it < 16; ++it) {  // zero h-section of slot0: chunks 2048..6143
      int chunk = it * 256 + tid;
      *(int4v*)(Abuf0 + (2048 + chunk) * 8) = (int4v){0, 0, 0, 0};
    }
  } else if (b == 1) {
    for (int k = 0; k < 6; ++k) flags[k * 256 + tid] = 0u;      // 1536 u32
  } else if (b < 6) {
    float* base = featacc + (b - 2) * 16384;                    // quarter = 16K f32
    for (int it = 0; it < 16; ++it)
      *(f32x4*)(base + (it * 256 + tid) * 4) = (f32x4){0.f, 0.f, 0.f, 0.f};
  } else if (b == 6) {
    float s = b_fx[tid];
    for (int k = 0; k < 64; ++k) s += W_fx[tid * 64 + k] * b_out[k];
    bcomb[tid] = s;
  } else {
    // Wcomb c-tile (b-7): c in [ (b-7)*16, +16 ), all dec
    int ct = b - 7;
    for (int it = 0; it < 16; ++it) {
      int o = it * 256 + tid;
      int cl = o >> 8, dec = o & 255;
      int c = ct * 16 + cl;
      float s = 0.f;
      for (int k = 0; k < 64; ++k) s += W_fx[c * 64 + k] * W_out[k * 256 + dec];
      int dwk = dec >> 5, kd = dec & 31;
      int l = (c & 15) + ((kd >> 3) << 4), j = kd & 7;
      Wcpack[((dwk * 16 + (c >> 4)) * 64 + l) * 8 + j] = f2bf(s);
    }
  }
}

// ---------------------------------------------------------------------------
// prep_ftf: ftf[t] = tanh(x_t @ W_fx^T + b_fx) as bf16 A-frags, all 256 t.
// ---------------------------------------------------------------------------
__global__ void prep_ftf(const float* __restrict__ x, const float* __restrict__ W_fx,
                         const float* __restrict__ b_fx, u16* __restrict__ ftf) {
  __shared__ __attribute__((aligned(16))) u16 fstage[64 * 264];
  const int t = blockIdx.x, tid = threadIdx.x;
  const int wv = tid >> 6, ln = tid & 63;
  const int c15 = ln & 15, qq = ln >> 4;
  short8 WfR[2][4];
#pragma unroll
  for (int kk = 0; kk < 2; ++kk)
#pragma unroll
    for (int nt = 0; nt < 4; ++nt)
      WfR[kk][nt] = cvt8(W_fx + ((wv * 4 + nt) * 16 + c15) * 64 + kk * 32 + qq * 8);
  float bfx_r[4];
#pragma unroll
  for (int nt = 0; nt < 4; ++nt) bfx_r[nt] = b_fx[(wv * 4 + nt) * 16 + c15];
  short8 xa[2][4];
#pragma unroll
  for (int kb = 0; kb < 2; ++kb)
#pragma unroll
    for (int mt = 0; mt < 4; ++mt)
      xa[kb][mt] = cvt8v(x + (t * 64 + mt * 16 + c15) * 64 + kb * 32 + qq * 8);
  f32x4 tf[4][4];
#pragma unroll
  for (int nt = 0; nt < 4; ++nt)
#pragma unroll
    for (int mt = 0; mt < 4; ++mt) tf[nt][mt] = (f32x4){0.f, 0.f, 0.f, 0.f};
#pragma unroll
  for (int kb = 0; kb < 2; ++kb)
#pragma unroll
    for (int nt = 0; nt < 4; ++nt)
#pragma unroll
      for (int mt = 0; mt < 4; ++mt)
        tf[nt][mt] = __builtin_amdgcn_mfma_f32_16x16x32_bf16(xa[kb][mt], WfR[kb][nt], tf[nt][mt], 0, 0, 0);
#pragma unroll
  for (int nt = 0; nt < 4; ++nt)
#pragma unroll
    for (int mt = 0; mt < 4; ++mt)
#pragma unroll
      for (int r2 = 0; r2 < 4; ++r2) {
        int row = mt * 16 + qq * 4 + r2;
        fstage[row * 264 + (wv * 4 + nt) * 16 + c15] = f2bf(fast_tanh(tf[nt][mt][r2] + bfx_r[nt]));
      }
  __syncthreads();
  u16* ftfb = ftf + t * 16384;
#pragma unroll
  for (int it = 0; it < 8; ++it) {
    int chunk = it * 256 + tid;
    int kb = chunk >> 8, l = chunk & 63;
    int m = ((chunk >> 6) & 3) * 16 + (l & 15);
    int k = kb * 32 + (l >> 4) * 8;
    *(short8*)(ftfb + chunk * 8) = *(const short8*)(fstage + m * 264 + k);
  }
}

// ---------------------------------------------------------------------------
// Persistent recurrent kernel. 73 WGs x 256 threads. Round-14 structure with
// SELF-SYNCHRONIZING LANES: the h data a lane loads at position ln is produced
// only by gate WGs with wg&3 == ln>>4, i.e. exactly the producers counted by
// hcnt[ln>>4]. Every lane polls its OWN counter (broadcast loads coalesce) and
// proceeds directly into its gather — no detector thread, no release barrier.
// fcnt is a single line polled by all lanes. Gate loop: 2 barriers (red/LSTM
// pair) instead of 4. The intra-WG barriers merge per-lane observations, so
// ring-reuse safety arguments carry over (writers have transitively observed
// all counters & fcnt before reuse). featacc zeroing issued right after the
// post-red barrier so it drains under LSTM compute.
// ---------------------------------------------------------------------------
__global__ void __launch_bounds__(256, 1)
rnn_kernel(const float* __restrict__ x, const float* __restrict__ msel,
           const float* __restrict__ W_ih, const float* __restrict__ W_hh,
           const float* __restrict__ b_ih, const float* __restrict__ b_hh,
           const float* __restrict__ W_hx, const float* __restrict__ b_hx,
           const float* __restrict__ W_out, const float* __restrict__ b_out,
           float* __restrict__ out,
           u16* __restrict__ Abase, u16* __restrict__ dbase,
           u32* __restrict__ flags, float* __restrict__ featacc,
           const float* __restrict__ bcomb, const u16* __restrict__ Wcpack,
           const u16* __restrict__ ftf) {
  __shared__ __attribute__((aligned(16))) char smem[109568];
  const int wgid = blockIdx.x;
  const int tid = threadIdx.x;
  const int wv = tid >> 6, ln = tid & 63;
  u32* dflag = flags + 1024;   // stride 16 u32
  u32* hcnt  = flags + 1168;   // 4 counters, stride 16
  u32* fcnt  = flags + 1232;   // 4 counters (featacc slots), stride 16

  if (wgid < GATE_WGS) {
    // ===== gate WG: kb remap kb = wv + kk*4 (kk 0,1 = feat; 2..5 = h) =====
    const int wg = wgid;
    float* red = (float*)smem;                 // [4 wv][8 tile][64][4] = 32KB
    u16* hstage = (u16*)(smem + 32768);        // 1KB
    short8 Breg[6][2];
#pragma unroll
    for (int kk = 0; kk < 6; ++kk) {
      int kb = wv + kk * 4;
#pragma unroll
      for (int nt = 0; nt < 2; ++nt) {
        int n = ln & 15, q = ln >> 4;
        int gate = nt * 2 + (n >> 3), unit = n & 7;
        int row = gate * 512 + wg * 8 + unit;
        int k = kb * 32 + q * 8;
        const float* src = (k < 256) ? (W_ih + row * 256 + k) : (W_hh + row * 512 + (k - 256));
        Breg[kk][nt] = cvt8(src);
      }
    }
    float bcomb_r[2][8];
#pragma unroll
    for (int kk = 0; kk < 2; ++kk)
#pragma unroll
      for (int j = 0; j < 8; ++j)
        bcomb_r[kk][j] = bcomb[(wv + kk * 4) * 32 + (ln >> 4) * 8 + j];
    float bsum_r[2][4];
#pragma unroll
    for (int it = 0; it < 2; ++it) {
      int u = (it * 256 + tid) & 7;
#pragma unroll
      for (int g = 0; g < 4; ++g) {
        int row = g * 512 + wg * 8 + u;
        bsum_r[it][g] = b_ih[row] + b_hh[row];
      }
    }
    float creg[2] = {0.f, 0.f};
    const int kbW = 8 + (wg >> 2), qW = wg & 3;   // this WG's h region
    int r = 0, rn = 1;
    for (int t = 0; t < SEQ; ++t) {
      // prefetch ftf[t] (plain cached loads, flag-independent) + msel[t]
      const u16* ftfb = ftf + t * 16384;
      short8 tf8[2][4];
#pragma unroll
      for (int kk = 0; kk < 2; ++kk) {
        int kb = wv + kk * 4;
#pragma unroll
        for (int mt = 0; mt < 4; ++mt)
          tf8[kk][mt] = *(const short8*)(ftfb + ((kb * 4 + mt) * 64 + ln) * 8);
      }
      float mixg = (t > 0) ? msel[t] : 0.f;
      // --- FEAT-FIRST, per-lane fcnt poll (single line, broadcast) ---
      if (t > 0)
        pollge(&fcnt[((t - 1) & 3) * 16], 8u * (((u32)(t - 1) >> 2) + 1u));
      short8 a[6][4];
      if (t == 0) {
#pragma unroll
        for (int kk = 0; kk < 2; ++kk)
#pragma unroll
          for (int mt = 0; mt < 4; ++mt)
            a[kk][mt] = tf8[kk][mt];
      } else {
        const float* fs = featacc + ((t - 1) & 3) * FACC_ELE;
#pragma unroll
        for (int kk = 0; kk < 2; ++kk) {
          int kb = wv + kk * 4;
#pragma unroll
          for (int mt = 0; mt < 4; ++mt) {
            int ch = (kb * 4 + mt) * 64 + ln;
            f32x4 lo = ldc16f(fs + ch * 8);
            f32x4 hi = ldc16f(fs + ch * 8 + 4);
            short8 tfv = tf8[kk][mt];
            short8 rr;
#pragma unroll
            for (int j = 0; j < 8; ++j) {
              float av = ((j < 4) ? lo[j] : hi[j - 4]) + bcomb_r[kk][j];
              float fv = mixg * fast_tanh(av) + (1.f - mixg) * bf2f((u16)tfv[j]);
              rr[j] = (short)f2bf(fv);
            }
            a[kk][mt] = rr;
          }
        }
      }
      // --- per-lane hcnt poll: counter (ln>>4) covers ALL producers of
      //     this lane's h positions; no barrier before the gather ---
      pollge(&hcnt[(ln >> 4) * 16], (u32)(16 * t));
      const u16* A = Abase + r * A_ELE;
      u16* An = Abase + rn * A_ELE;
#pragma unroll
      for (int kk = 2; kk < 6; ++kk) {
        int kb = wv + kk * 4;
#pragma unroll
        for (int mt = 0; mt < 4; ++mt)
          a[kk][mt] = ldc16(A + ((kb * 4 + mt) * 64 + ln) * 8);
      }
      f32x4 acc[2][4];
#pragma unroll
      for (int nt = 0; nt < 2; nt++)
#pragma unroll
        for (int mt = 0; mt < 4; mt++) acc[nt][mt] = (f32x4){0.f, 0.f, 0.f, 0.f};
#pragma unroll
      for (int kk = 0; kk < 6; ++kk)
#pragma unroll
        for (int nt = 0; nt < 2; nt++)
#pragma unroll
          for (int mt = 0; mt < 4; mt++)
            acc[nt][mt] = __builtin_amdgcn_mfma_f32_16x16x32_bf16(a[kk][mt], Breg[kk][nt], acc[nt][mt], 0, 0, 0);
      // one-shot 4-wave reduction staging
#pragma unroll
      for (int nt = 0; nt < 2; nt++)
#pragma unroll
        for (int mt = 0; mt < 4; mt++)
          *(f32x4*)(red + ((wv * 8 + nt * 4 + mt) * 64 + ln) * 4) = acc[nt][mt];
      __syncthreads();
      // zero featacc slot (t+2)&3 EARLY (safe: barrier merged all polls);
      // drains during LSTM compute below
      if (tid < 64) {
        u64 zq[2] = {0ull, 0ull};
        u16* fz = (u16*)featacc + ((t + 2) & 3) * 32768 + wg * 512 + tid * 8;
        stc16(fz, zq);
      }
      // LSTM cell: 512 (m,u) items, 2/thread; sum 4 wave-partials inline
#pragma unroll
      for (int it = 0; it < 2; ++it) {
        int item = it * 256 + tid;
        int m = item >> 3, u = item & 7;
        int mt = m >> 4, lq = ((m & 15) >> 2) * 16, reg = m & 3;
        float g4[4];
#pragma unroll
        for (int g = 0; g < 4; ++g) {
          float s = bsum_r[it][g];
          int base = ((g >> 1) * 4 + mt) * 64 + lq + (g & 1) * 8 + u;
#pragma unroll
          for (int w = 0; w < 4; ++w) s += red[(w * 8 * 64 + base) * 4 + reg];
          g4[g] = s;
        }
        float ii = fast_sig(g4[0]), ff = fast_sig(g4[1]);
        float gg = fast_tanh(g4[2]), oo = fast_sig(g4[3]);
        float cn = ff * creg[it] + ii * gg;
        creg[it] = cn;
        float h = oo * fast_tanh(cn);
        hstage[(mt * 16 + (m & 15)) * 8 + u] = f2bf(h);
      }
      __syncthreads();
      if (tid < 64) {   // 16B coherent stores of this WG's 1KB h region
        int mt2 = tid >> 4, m15 = tid & 15;
        u16* dst = An + (((kbW * 4 + mt2) * 64 + qW * 16 + m15) * 8);
        stc16(dst, (const u64*)(hstage + tid * 8));
        VMCNT0();
        if (tid == 0)
          (void)__hip_atomic_fetch_add(&hcnt[(wg & 3) * 16], 1u,
                                       __ATOMIC_RELAXED, __HIP_MEMORY_SCOPE_AGENT);
      }
      r = rn; rn = (rn == 2) ? 0 : rn + 1;
    }
  } else if (wgid < GATE_WGS + D_WGS) {
    // ===== d WG: d slice + Wcomb feat-partial atomic-add =====
    const int dw = wgid - GATE_WGS;
    float* red = (float*)smem;                 // 32KB
    u16* dstage = (u16*)(smem + 32768);        // 4KB
    short8 Breg[4][2];
#pragma unroll
    for (int kk = 0; kk < 4; ++kk) {
      int kbh = wv * 4 + kk;
#pragma unroll
      for (int nt = 0; nt < 2; ++nt) {
        int n = ln & 15, q = ln >> 4;
        int row = dw * 32 + nt * 16 + n;
        int k = kbh * 32 + q * 8;
        Breg[kk][nt] = cvt8(W_hx + row * 512 + k);
      }
    }
    short8 WcB[4];   // Wcomb B-frags: this wave's 4 c-tiles, this WG's 32 dec k's
#pragma unroll
    for (int nt = 0; nt < 4; ++nt)
      WcB[nt] = *(const short8*)(Wcpack + ((dw * 16 + wv * 4 + nt) * 64 + ln) * 8);
    float bias_r[8];
#pragma unroll
    for (int it = 0; it < 8; ++it) bias_r[it] = b_hx[dw * 32 + ((it * 256 + tid) & 31)];
    int r = 0, rn = 1;
    for (int t = 0; t < SEQ; ++t) {
      // per-lane hcnt poll (same producer mapping as gates); no barrier
      pollge(&hcnt[(ln >> 4) * 16], (u32)(16 * t));
      const u16* A = Abase + r * A_ELE;
      u16* dbufR = dbase + (t & 1) * D_ELE;
      short8 a[4][4];
#pragma unroll
      for (int kk = 0; kk < 4; ++kk)
#pragma unroll
        for (int mt = 0; mt < 4; ++mt)
          a[kk][mt] = ldc16(A + (((8 + wv * 4 + kk) * 4 + mt) * 64 + ln) * 8);
      f32x4 acc[2][4];
#pragma unroll
      for (int nt = 0; nt < 2; nt++)
#pragma unroll
        for (int mt = 0; mt < 4; mt++) acc[nt][mt] = (f32x4){0.f, 0.f, 0.f, 0.f};
#pragma unroll
      for (int kk = 0; kk < 4; ++kk)
#pragma unroll
        for (int nt = 0; nt < 2; nt++)
#pragma unroll
          for (int mt = 0; mt < 4; mt++)
            acc[nt][mt] = __builtin_amdgcn_mfma_f32_16x16x32_bf16(a[kk][mt], Breg[kk][nt], acc[nt][mt], 0, 0, 0);
#pragma unroll
      for (int nt = 0; nt < 2; nt++)
#pragma unroll
        for (int mt = 0; mt < 4; mt++)
          *(f32x4*)(red + ((wv * 8 + nt * 4 + mt) * 64 + ln) * 4) = acc[nt][mt];
      __syncthreads();
#pragma unroll
      for (int it = 0; it < 8; ++it) {          // 2048 outputs, 8/thread
        int item = it * 256 + tid;
        int m = item >> 5, c = item & 31;
        int mt = m >> 4, lq = ((m & 15) >> 2) * 16, reg = m & 3;
        float s = bias_r[it];
        int base = ((c >> 4) * 4 + mt) * 64 + lq + (c & 15);
#pragma unroll
        for (int w = 0; w < 4; ++w) s += red[(w * 8 * 64 + base) * 4 + reg];
        dstage[((mt * 4 + (c >> 3)) * 16 + (m & 15)) * 8 + (c & 7)] = f2bf(fast_tanh(s));
      }
      __syncthreads();
      // d publish for the lazy y WG
      stc16(dbufR + (dw * 256 + tid) * 8, (const u64*)(dstage + tid * 8));
      // feat partial: A = d slice frags (from dstage), B = WcB, K=32
      short8 ad[4];
#pragma unroll
      for (int mt = 0; mt < 4; ++mt)
        ad[mt] = *(const short8*)(dstage + ((mt * 4 + (ln >> 4)) * 16 + (ln & 15)) * 8);
      f32x4 pacc[4][4];
#pragma unroll
      for (int nt = 0; nt < 4; ++nt)
#pragma unroll
        for (int mt = 0; mt < 4; ++mt) pacc[nt][mt] = (f32x4){0.f, 0.f, 0.f, 0.f};
#pragma unroll
      for (int nt = 0; nt < 4; ++nt)
#pragma unroll
        for (int mt = 0; mt < 4; ++mt)
          pacc[nt][mt] = __builtin_amdgcn_mfma_f32_16x16x32_bf16(ad[mt], WcB[nt], pacc[nt][mt], 0, 0, 0);
      {
        float* fs = featacc + (t & 3) * FACC_ELE;
#pragma unroll
        for (int nt = 0; nt < 4; ++nt) {
          int c = (wv * 4 + nt) * 16 + (ln & 15);
          int cb = (c >> 5) * 2048 + ((c & 31) >> 3) * 128 + (c & 7);
#pragma unroll
          for (int mt = 0; mt < 4; ++mt)
#pragma unroll
            for (int reg = 0; reg < 4; ++reg)
              atadd(fs + cb + mt * 512 + ((ln >> 4) * 4 + reg) * 8, pacc[nt][mt][reg]);
        }
      }
      VMCNT0();
      __syncthreads();
      if (tid == 0) {
        setflag(&dflag[dw * 16], (u32)(t + 1));
        (void)__hip_atomic_fetch_add(&fcnt[(t & 3) * 16], 1u,
                                     __ATOMIC_RELAXED, __HIP_MEMORY_SCOPE_AGENT);
      }
      r = rn; rn = (rn == 2) ? 0 : rn + 1;
    }
  } else {
    // ===== lazy y WG (off the recurrence): y = d @ W_out^T + b_out =====
    float* red = (float*)smem;                 // [4 wv][16 tile][64][4] = 64KB
    const int c15 = ln & 15, qq = ln >> 4;
    short8 WoR[2][4];
#pragma unroll
    for (int kk = 0; kk < 2; ++kk) {
      int koffo = (wv * 2 + kk) * 32 + qq * 8;
#pragma unroll
      for (int nt = 0; nt < 4; ++nt)
        WoR[kk][nt] = cvt8(W_out + (nt * 16 + c15) * 256 + koffo);
    }
    float bout_r = b_out[wv * 16 + c15];
    for (int t = 0; t < SEQ; ++t) {
      if (tid < 8) pollge(&dflag[tid * 16], (u32)(t + 1));
      __syncthreads();
      const u16* dbufR = dbase + (t & 1) * D_ELE;
      short8 da[2][4];
#pragma unroll
      for (int kk = 0; kk < 2; ++kk)
#pragma unroll
        for (int mt = 0; mt < 4; ++mt)
          da[kk][mt] = ldc16(dbufR + (((wv * 2 + kk) * 4 + mt) * 64 + ln) * 8);
      f32x4 acc[4][4];
#pragma unroll
      for (int nt = 0; nt < 4; nt++)
#pragma unroll
        for (int mt = 0; mt < 4; mt++) acc[nt][mt] = (f32x4){0.f, 0.f, 0.f, 0.f};
#pragma unroll
      for (int kk = 0; kk < 2; ++kk)
#pragma unroll
        for (int nt = 0; nt < 4; nt++)
#pragma unroll
          for (int mt = 0; mt < 4; mt++)
            acc[nt][mt] = __builtin_amdgcn_mfma_f32_16x16x32_bf16(da[kk][mt], WoR[kk][nt], acc[nt][mt], 0, 0, 0);
#pragma unroll
      for (int nt = 0; nt < 4; nt++)
#pragma unroll
        for (int mt = 0; mt < 4; mt++)
          *(f32x4*)(red + ((wv * 16 + nt * 4 + mt) * 64 + ln) * 4) = acc[nt][mt];
      __syncthreads();
#pragma unroll
      for (int mt = 0; mt < 4; ++mt) {
        f32x4 s = (f32x4){0.f, 0.f, 0.f, 0.f};
#pragma unroll
        for (int w2 = 0; w2 < 4; ++w2)
          s += *(const f32x4*)(red + ((w2 * 16 + wv * 4 + mt) * 64 + ln) * 4);
#pragma unroll
        for (int r2 = 0; r2 < 4; ++r2) {
          int row = mt * 16 + qq * 4 + r2;
          out[t * 4096 + row * 64 + wv * 16 + c15] = s[r2] + bout_r;
        }
      }
      __syncthreads();
    }
  }
}

extern "C" void kernel_launch(void* const* d_in, const int* in_sizes, int n_in,
                              void* d_out, int out_size, void* d_ws, size_t ws_size,
                              hipStream_t stream) {
  const float* x     = (const float*)d_in[0];
  const float* msel  = (const float*)d_in[1];
  const float* W_fx  = (const float*)d_in[2];
  const float* b_fx  = (const float*)d_in[3];
  const float* W_ih  = (const float*)d_in[4];
  const float* W_hh  = (const float*)d_in[5];
  const float* b_ih  = (const float*)d_in[6];
  const float* b_hh  = (const float*)d_in[7];
  const float* W_hx  = (const float*)d_in[8];
  const float* b_hx  = (const float*)d_in[9];
  const float* W_out = (const float*)d_in[10];
  const float* b_out = (const float*)d_in[11];

  uint8_t* ws = (uint8_t*)d_ws;
  u16*   Abase   = (u16*)ws;                  // ring of 3 x 98304 B
  u16*   dbase   = (u16*)(ws + 294912);       // ring of 2 x 32768 B
  u32*   flags   = (u32*)(ws + 360448);       // 6144 B (u32[1536])
  float* featacc = (float*)(ws + 368640);     // 4 x 65536 B
  float* bcomb   = (float*)(ws + 630784);     // 1024 B
  u16*   Wcpack  = (u16*)(ws + 631808);       // 131072 B
  u16*   ftf     = (u16*)(ws + 762880);       // 256 x 32768 B = 8 MB

  prep_misc<<<23, 256, 0, stream>>>(W_fx, b_fx, W_out, b_out,
                                    Abase, flags, featacc, bcomb, Wcpack);
  prep_ftf<<<256, 256, 0, stream>>>(x, W_fx, b_fx, ftf);
  rnn_kernel<<<NWG, 256, 0, stream>>>(x, msel, W_ih, W_hh, b_ih, b_hh,
                                      W_hx, b_hx, W_out, b_out,
                                      (float*)d_out, Abase, dbase, flags,
                                      featacc, bcomb, Wcpack, ftf);
}

// Round 16
// 2137.332 us; speedup vs baseline: 1.0379x; 1.0379x over previous
//
#include <hip/hip_runtime.h>
#include <stdint.h>

typedef unsigned short u16;
typedef unsigned int u32;
typedef unsigned long long u64;
typedef __attribute__((ext_vector_type(8))) short short8;   // 8 x bf16
typedef __attribute__((ext_vector_type(4))) float f32x4;
typedef __attribute__((ext_vector_type(4))) int int4v;

#define SEQ 256
#define GATE_WGS 64
#define D_WGS 8
#define NWG 73          // 64 gate + 8 d (feat-partial producers) + 1 lazy y
#define A_ELE 49152     // elements per A ring slot (bf16); feat section unused
#define D_ELE 16384
#define FACC_ELE 16384  // f32 per featacc slot (64 m x 256 c)

__device__ __forceinline__ u16 f2bf(float f) {
  u32 u = __float_as_uint(f);
  u += 0x7FFFu + ((u >> 16) & 1u);
  return (u16)(u >> 16);
}
__device__ __forceinline__ float bf2f(u16 v) {
  return __uint_as_float(((u32)v) << 16);
}
__device__ __forceinline__ short8 cvt8(const float* __restrict__ p) {
  short8 r;
#pragma unroll
  for (int j = 0; j < 8; ++j) r[j] = (short)f2bf(p[j]);
  return r;
}
__device__ __forceinline__ short8 cvt8v(const float* __restrict__ p) {  // 2x float4
  f32x4 a = *(const f32x4*)p, b = *(const f32x4*)(p + 4);
  short8 r;
#pragma unroll
  for (int j = 0; j < 4; ++j) { r[j] = (short)f2bf(a[j]); r[4 + j] = (short)f2bf(b[j]); }
  return r;
}
__device__ __forceinline__ float fast_tanh(float x) {
  return 1.0f - 2.0f / (1.0f + __expf(2.0f * x));
}
__device__ __forceinline__ float fast_sig(float x) {
  return 1.0f / (1.0f + __expf(-x));
}

union V16 { short8 s; u64 q[2]; };
// device-coherent load/store (bypass L1/L2 -> coherence point), fence-free
__device__ __forceinline__ short8 ldc16(const u16* p) {
  V16 v;
  v.q[0] = __hip_atomic_load((const u64*)p,     __ATOMIC_RELAXED, __HIP_MEMORY_SCOPE_AGENT);
  v.q[1] = __hip_atomic_load((const u64*)p + 1, __ATOMIC_RELAXED, __HIP_MEMORY_SCOPE_AGENT);
  return v.s;
}
__device__ __forceinline__ f32x4 ldc16f(const float* p) {
  union { f32x4 f; u64 q[2]; } v;
  v.q[0] = __hip_atomic_load((const u64*)p,     __ATOMIC_RELAXED, __HIP_MEMORY_SCOPE_AGENT);
  v.q[1] = __hip_atomic_load((const u64*)p + 1, __ATOMIC_RELAXED, __HIP_MEMORY_SCOPE_AGENT);
  return v.f;
}
__device__ __forceinline__ void stc16(u16* p, const u64* s) {
  __hip_atomic_store((u64*)p,     s[0], __ATOMIC_RELAXED, __HIP_MEMORY_SCOPE_AGENT);
  __hip_atomic_store((u64*)p + 1, s[1], __ATOMIC_RELAXED, __HIP_MEMORY_SCOPE_AGENT);
}
__device__ __forceinline__ void atadd(float* p, float v) {
  (void)__hip_atomic_fetch_add(p, v, __ATOMIC_RELAXED, __HIP_MEMORY_SCOPE_AGENT);
}
__device__ __forceinline__ void pollge(u32* p, u32 v) {
  while (__hip_atomic_load(p, __ATOMIC_RELAXED, __HIP_MEMORY_SCOPE_AGENT) < v) {}
}
__device__ __forceinline__ void setflag(u32* p, u32 v) {
  __hip_atomic_store(p, v, __ATOMIC_RELAXED, __HIP_MEMORY_SCOPE_AGENT);
}
// per-wave store drain: prior coherent stores reach coherence point before flag
#define VMCNT0() asm volatile("s_waitcnt vmcnt(0)" ::: "memory")

// ---------------------------------------------------------------------------
// prep_misc: zero h slot0 / flags / featacc; bcomb = W_fx@b_out + b_fx;
// Wcpack = bf16 MFMA-B-frag pack of Wcomb = W_fx @ W_out  [256 c][256 dec].
// ---------------------------------------------------------------------------
__global__ void prep_misc(const float* __restrict__ W_fx, const float* __restrict__ b_fx,
                          const float* __restrict__ W_out, const float* __restrict__ b_out,
                          u16* __restrict__ Abuf0, u32* __restrict__ flags,
                          float* __restrict__ featacc, float* __restrict__ bcomb,
                          u16* __restrict__ Wcpack) {
  int b = blockIdx.x, tid = threadIdx.x;
  if (b == 0) {
    for (int it = 0; it < 16; ++it) {  // zero h-section of slot0: chunks 2048..6143
      int chunk = it * 256 + tid;
      *(int4v*)(Abuf0 + (2048 + chunk) * 8) = (int4v){0, 0, 0, 0};
    }
  } else if (b == 1) {
    for (int k = 0; k < 6; ++k) flags[k * 256 + tid] = 0u;      // 1536 u32
  } else if (b < 6) {
    float* base = featacc + (b - 2) * 16384;                    // quarter = 16K f32
    for (int it = 0; it < 16; ++it)
      *(f32x4*)(base + (it * 256 + tid) * 4) = (f32x4){0.f, 0.f, 0.f, 0.f};
  } else if (b == 6) {
    float s = b_fx[tid];
    for (int k = 0; k < 64; ++k) s += W_fx[tid * 64 + k] * b_out[k];
    bcomb[tid] = s;
  } else {
    // Wcomb c-tile (b-7): c in [ (b-7)*16, +16 ), all dec
    int ct = b - 7;
    for (int it = 0; it < 16; ++it) {
      int o = it * 256 + tid;
      int cl = o >> 8, dec = o & 255;
      int c = ct * 16 + cl;
      float s = 0.f;
      for (int k = 0; k < 64; ++k) s += W_fx[c * 64 + k] * W_out[k * 256 + dec];
      int dwk = dec >> 5, kd = dec & 31;
      int l = (c & 15) + ((kd >> 3) << 4), j = kd & 7;
      Wcpack[((dwk * 16 + (c >> 4)) * 64 + l) * 8 + j] = f2bf(s);
    }
  }
}

// ---------------------------------------------------------------------------
// prep_ftf: ftf[t] = tanh(x_t @ W_fx^T + b_fx) as bf16 A-frags, all 256 t.
// ---------------------------------------------------------------------------
__global__ void prep_ftf(const float* __restrict__ x, const float* __restrict__ W_fx,
                         const float* __restrict__ b_fx, u16* __restrict__ ftf) {
  __shared__ __attribute__((aligned(16))) u16 fstage[64 * 264];
  const int t = blockIdx.x, tid = threadIdx.x;
  const int wv = tid >> 6, ln = tid & 63;
  const int c15 = ln & 15, qq = ln >> 4;
  short8 WfR[2][4];
#pragma unroll
  for (int kk = 0; kk < 2; ++kk)
#pragma unroll
    for (int nt = 0; nt < 4; ++nt)
      WfR[kk][nt] = cvt8(W_fx + ((wv * 4 + nt) * 16 + c15) * 64 + kk * 32 + qq * 8);
  float bfx_r[4];
#pragma unroll
  for (int nt = 0; nt < 4; ++nt) bfx_r[nt] = b_fx[(wv * 4 + nt) * 16 + c15];
  short8 xa[2][4];
#pragma unroll
  for (int kb = 0; kb < 2; ++kb)
#pragma unroll
    for (int mt = 0; mt < 4; ++mt)
      xa[kb][mt] = cvt8v(x + (t * 64 + mt * 16 + c15) * 64 + kb * 32 + qq * 8);
  f32x4 tf[4][4];
#pragma unroll
  for (int nt = 0; nt < 4; ++nt)
#pragma unroll
    for (int mt = 0; mt < 4; ++mt) tf[nt][mt] = (f32x4){0.f, 0.f, 0.f, 0.f};
#pragma unroll
  for (int kb = 0; kb < 2; ++kb)
#pragma unroll
    for (int nt = 0; nt < 4; ++nt)
#pragma unroll
      for (int mt = 0; mt < 4; ++mt)
        tf[nt][mt] = __builtin_amdgcn_mfma_f32_16x16x32_bf16(xa[kb][mt], WfR[kb][nt], tf[nt][mt], 0, 0, 0);
#pragma unroll
  for (int nt = 0; nt < 4; ++nt)
#pragma unroll
    for (int mt = 0; mt < 4; ++mt)
#pragma unroll
      for (int r2 = 0; r2 < 4; ++r2) {
        int row = mt * 16 + qq * 4 + r2;
        fstage[row * 264 + (wv * 4 + nt) * 16 + c15] = f2bf(fast_tanh(tf[nt][mt][r2] + bfx_r[nt]));
      }
  __syncthreads();
  u16* ftfb = ftf + t * 16384;
#pragma unroll
  for (int it = 0; it < 8; ++it) {
    int chunk = it * 256 + tid;
    int kb = chunk >> 8, l = chunk & 63;
    int m = ((chunk >> 6) & 3) * 16 + (l & 15);
    int k = kb * 32 + (l >> 4) * 8;
    *(short8*)(ftfb + chunk * 8) = *(const short8*)(fstage + m * 264 + k);
  }
}

// ---------------------------------------------------------------------------
// Persistent recurrent kernel. 73 WGs x 256 threads. Round-14 structure
// (champion: feat-first gates, detector-thread polls) + early featacc zero:
// the 1KB zero store is issued right after the post-red barrier (safe: all
// polls transitively observed) so it drains under the LSTM compute and the
// critical-path VMCNT0 covers only the 1KB h store.
//   hcnt[j] += 1 (j=wg&3) after gate wg stored h_{t+1}
//   d WGs: h_t -> d_t; atomic-add Wcomb partials into featacc[t&3];
//     drain; dflag=t+1; fcnt[t&3]++.  y WG off-chain via dflag.
// featacc 4-slot ring: add@t, read@t+1, zero@t+2 (by gates, race-free), idle.
// ---------------------------------------------------------------------------
__global__ void __launch_bounds__(256, 1)
rnn_kernel(const float* __restrict__ x, const float* __restrict__ msel,
           const float* __restrict__ W_ih, const float* __restrict__ W_hh,
           const float* __restrict__ b_ih, const float* __restrict__ b_hh,
           const float* __restrict__ W_hx, const float* __restrict__ b_hx,
           const float* __restrict__ W_out, const float* __restrict__ b_out,
           float* __restrict__ out,
           u16* __restrict__ Abase, u16* __restrict__ dbase,
           u32* __restrict__ flags, float* __restrict__ featacc,
           const float* __restrict__ bcomb, const u16* __restrict__ Wcpack,
           const u16* __restrict__ ftf) {
  __shared__ __attribute__((aligned(16))) char smem[109568];
  const int wgid = blockIdx.x;
  const int tid = threadIdx.x;
  const int wv = tid >> 6, ln = tid & 63;
  u32* dflag = flags + 1024;   // stride 16 u32
  u32* hcnt  = flags + 1168;   // 4 counters, stride 16
  u32* fcnt  = flags + 1232;   // 4 counters (featacc slots), stride 16

  if (wgid < GATE_WGS) {
    // ===== gate WG: kb remap kb = wv + kk*4 (kk 0,1 = feat; 2..5 = h) =====
    const int wg = wgid;
    float* red = (float*)smem;                 // [4 wv][8 tile][64][4] = 32KB
    u16* hstage = (u16*)(smem + 32768);        // 1KB
    short8 Breg[6][2];
#pragma unroll
    for (int kk = 0; kk < 6; ++kk) {
      int kb = wv + kk * 4;
#pragma unroll
      for (int nt = 0; nt < 2; ++nt) {
        int n = ln & 15, q = ln >> 4;
        int gate = nt * 2 + (n >> 3), unit = n & 7;
        int row = gate * 512 + wg * 8 + unit;
        int k = kb * 32 + q * 8;
        const float* src = (k < 256) ? (W_ih + row * 256 + k) : (W_hh + row * 512 + (k - 256));
        Breg[kk][nt] = cvt8(src);
      }
    }
    float bcomb_r[2][8];
#pragma unroll
    for (int kk = 0; kk < 2; ++kk)
#pragma unroll
      for (int j = 0; j < 8; ++j)
        bcomb_r[kk][j] = bcomb[(wv + kk * 4) * 32 + (ln >> 4) * 8 + j];
    float bsum_r[2][4];
#pragma unroll
    for (int it = 0; it < 2; ++it) {
      int u = (it * 256 + tid) & 7;
#pragma unroll
      for (int g = 0; g < 4; ++g) {
        int row = g * 512 + wg * 8 + u;
        bsum_r[it][g] = b_ih[row] + b_hh[row];
      }
    }
    float creg[2] = {0.f, 0.f};
    const int kbW = 8 + (wg >> 2), qW = wg & 3;   // this WG's h region
    int r = 0, rn = 1;
    for (int t = 0; t < SEQ; ++t) {
      // prefetch ftf[t] (plain cached loads, flag-independent) + msel[t]
      const u16* ftfb = ftf + t * 16384;
      short8 tf8[2][4];
#pragma unroll
      for (int kk = 0; kk < 2; ++kk) {
        int kb = wv + kk * 4;
#pragma unroll
        for (int mt = 0; mt < 4; ++mt)
          tf8[kk][mt] = *(const short8*)(ftfb + ((kb * 4 + mt) * 64 + ln) * 8);
      }
      float mixg = (t > 0) ? msel[t] : 0.f;
      // --- FEAT-FIRST: feat_t is ready early (depends on h_{t-1}) ---
      if (tid == 64 && t > 0)
        pollge(&fcnt[((t - 1) & 3) * 16], 8u * (((u32)(t - 1) >> 2) + 1u));
      __syncthreads();
      short8 a[6][4];
      if (t == 0) {
#pragma unroll
        for (int kk = 0; kk < 2; ++kk)
#pragma unroll
          for (int mt = 0; mt < 4; ++mt)
            a[kk][mt] = tf8[kk][mt];
      } else {
        const float* fs = featacc + ((t - 1) & 3) * FACC_ELE;
#pragma unroll
        for (int kk = 0; kk < 2; ++kk) {
          int kb = wv + kk * 4;
#pragma unroll
          for (int mt = 0; mt < 4; ++mt) {
            int ch = (kb * 4 + mt) * 64 + ln;
            f32x4 lo = ldc16f(fs + ch * 8);
            f32x4 hi = ldc16f(fs + ch * 8 + 4);
            short8 tfv = tf8[kk][mt];
            short8 rr;
#pragma unroll
            for (int j = 0; j < 8; ++j) {
              float av = ((j < 4) ? lo[j] : hi[j - 4]) + bcomb_r[kk][j];
              float fv = mixg * fast_tanh(av) + (1.f - mixg) * bf2f((u16)tfv[j]);
              rr[j] = (short)f2bf(fv);
            }
            a[kk][mt] = rr;
          }
        }
      }
      // --- NOW wait for h_t; only h work remains on the critical path ---
      if (tid < 4) pollge(&hcnt[tid * 16], (u32)(16 * t));
      __syncthreads();
      const u16* A = Abase + r * A_ELE;
      u16* An = Abase + rn * A_ELE;
#pragma unroll
      for (int kk = 2; kk < 6; ++kk) {
        int kb = wv + kk * 4;
#pragma unroll
        for (int mt = 0; mt < 4; ++mt)
          a[kk][mt] = ldc16(A + ((kb * 4 + mt) * 64 + ln) * 8);
      }
      f32x4 acc[2][4];
#pragma unroll
      for (int nt = 0; nt < 2; nt++)
#pragma unroll
        for (int mt = 0; mt < 4; mt++) acc[nt][mt] = (f32x4){0.f, 0.f, 0.f, 0.f};
#pragma unroll
      for (int kk = 0; kk < 6; ++kk)
#pragma unroll
        for (int nt = 0; nt < 2; nt++)
#pragma unroll
          for (int mt = 0; mt < 4; mt++)
            acc[nt][mt] = __builtin_amdgcn_mfma_f32_16x16x32_bf16(a[kk][mt], Breg[kk][nt], acc[nt][mt], 0, 0, 0);
      // one-shot 4-wave reduction staging
#pragma unroll
      for (int nt = 0; nt < 2; nt++)
#pragma unroll
        for (int mt = 0; mt < 4; mt++)
          *(f32x4*)(red + ((wv * 8 + nt * 4 + mt) * 64 + ln) * 4) = acc[nt][mt];
      __syncthreads();
      // EARLY featacc zero: slot (t+2)&3 is quiescent; all polls observed
      // (barriers above). Store drains under the LSTM compute; the final
      // VMCNT0 (before hcnt) then covers only the 1KB h store + this.
      if (tid < 64) {
        u64 zq[2] = {0ull, 0ull};
        u16* fz = (u16*)featacc + ((t + 2) & 3) * 32768 + wg * 512 + tid * 8;
        stc16(fz, zq);
      }
      // LSTM cell: 512 (m,u) items, 2/thread; sum 4 wave-partials inline
#pragma unroll
      for (int it = 0; it < 2; ++it) {
        int item = it * 256 + tid;
        int m = item >> 3, u = item & 7;
        int mt = m >> 4, lq = ((m & 15) >> 2) * 16, reg = m & 3;
        float g4[4];
#pragma unroll
        for (int g = 0; g < 4; ++g) {
          float s = bsum_r[it][g];
          int base = ((g >> 1) * 4 + mt) * 64 + lq + (g & 1) * 8 + u;
#pragma unroll
          for (int w = 0; w < 4; ++w) s += red[(w * 8 * 64 + base) * 4 + reg];
          g4[g] = s;
        }
        float ii = fast_sig(g4[0]), ff = fast_sig(g4[1]);
        float gg = fast_tanh(g4[2]), oo = fast_sig(g4[3]);
        float cn = ff * creg[it] + ii * gg;
        creg[it] = cn;
        float h = oo * fast_tanh(cn);
        hstage[(mt * 16 + (m & 15)) * 8 + u] = f2bf(h);
      }
      __syncthreads();
      if (tid < 64) {   // 16B coherent stores of this WG's 1KB h region
        int mt2 = tid >> 4, m15 = tid & 15;
        u16* dst = An + (((kbW * 4 + mt2) * 64 + qW * 16 + m15) * 8);
        stc16(dst, (const u64*)(hstage + tid * 8));
        VMCNT0();
        if (tid == 0)
          (void)__hip_atomic_fetch_add(&hcnt[(wg & 3) * 16], 1u,
                                       __ATOMIC_RELAXED, __HIP_MEMORY_SCOPE_AGENT);
      }
      r = rn; rn = (rn == 2) ? 0 : rn + 1;
    }
  } else if (wgid < GATE_WGS + D_WGS) {
    // ===== d WG: d slice + Wcomb feat-partial atomic-add =====
    const int dw = wgid - GATE_WGS;
    float* red = (float*)smem;                 // 32KB
    u16* dstage = (u16*)(smem + 32768);        // 4KB
    short8 Breg[4][2];
#pragma unroll
    for (int kk = 0; kk < 4; ++kk) {
      int kbh = wv * 4 + kk;
#pragma unroll
      for (int nt = 0; nt < 2; ++nt) {
        int n = ln & 15, q = ln >> 4;
        int row = dw * 32 + nt * 16 + n;
        int k = kbh * 32 + q * 8;
        Breg[kk][nt] = cvt8(W_hx + row * 512 + k);
      }
    }
    short8 WcB[4];   // Wcomb B-frags: this wave's 4 c-tiles, this WG's 32 dec k's
#pragma unroll
    for (int nt = 0; nt < 4; ++nt)
      WcB[nt] = *(const short8*)(Wcpack + ((dw * 16 + wv * 4 + nt) * 64 + ln) * 8);
    float bias_r[8];
#pragma unroll
    for (int it = 0; it < 8; ++it) bias_r[it] = b_hx[dw * 32 + ((it * 256 + tid) & 31)];
    int r = 0, rn = 1;
    for (int t = 0; t < SEQ; ++t) {
      if (tid < 4) pollge(&hcnt[tid * 16], (u32)(16 * t));
      __syncthreads();
      const u16* A = Abase + r * A_ELE;
      u16* dbufR = dbase + (t & 1) * D_ELE;
      short8 a[4][4];
#pragma unroll
      for (int kk = 0; kk < 4; ++kk)
#pragma unroll
        for (int mt = 0; mt < 4; ++mt)
          a[kk][mt] = ldc16(A + (((8 + wv * 4 + kk) * 4 + mt) * 64 + ln) * 8);
      f32x4 acc[2][4];
#pragma unroll
      for (int nt = 0; nt < 2; nt++)
#pragma unroll
        for (int mt = 0; mt < 4; mt++) acc[nt][mt] = (f32x4){0.f, 0.f, 0.f, 0.f};
#pragma unroll
      for (int kk = 0; kk < 4; ++kk)
#pragma unroll
        for (int nt = 0; nt < 2; nt++)
#pragma unroll
          for (int mt = 0; mt < 4; mt++)
            acc[nt][mt] = __builtin_amdgcn_mfma_f32_16x16x32_bf16(a[kk][mt], Breg[kk][nt], acc[nt][mt], 0, 0, 0);
#pragma unroll
      for (int nt = 0; nt < 2; nt++)
#pragma unroll
        for (int mt = 0; mt < 4; mt++)
          *(f32x4*)(red + ((wv * 8 + nt * 4 + mt) * 64 + ln) * 4) = acc[nt][mt];
      __syncthreads();
#pragma unroll
      for (int it = 0; it < 8; ++it) {          // 2048 outputs, 8/thread
        int item = it * 256 + tid;
        int m = item >> 5, c = item & 31;
        int mt = m >> 4, lq = ((m & 15) >> 2) * 16, reg = m & 3;
        float s = bias_r[it];
        int base = ((c >> 4) * 4 + mt) * 64 + lq + (c & 15);
#pragma unroll
        for (int w = 0; w < 4; ++w) s += red[(w * 8 * 64 + base) * 4 + reg];
        dstage[((mt * 4 + (c >> 3)) * 16 + (m & 15)) * 8 + (c & 7)] = f2bf(fast_tanh(s));
      }
      __syncthreads();
      // d publish for the lazy y WG
      stc16(dbufR + (dw * 256 + tid) * 8, (const u64*)(dstage + tid * 8));
      // feat partial: A = d slice frags (from dstage), B = WcB, K=32
      short8 ad[4];
#pragma unroll
      for (int mt = 0; mt < 4; ++mt)
        ad[mt] = *(const short8*)(dstage + ((mt * 4 + (ln >> 4)) * 16 + (ln & 15)) * 8);
      f32x4 pacc[4][4];
#pragma unroll
      for (int nt = 0; nt < 4; ++nt)
#pragma unroll
        for (int mt = 0; mt < 4; ++mt) pacc[nt][mt] = (f32x4){0.f, 0.f, 0.f, 0.f};
#pragma unroll
      for (int nt = 0; nt < 4; ++nt)
#pragma unroll
        for (int mt = 0; mt < 4; ++mt)
          pacc[nt][mt] = __builtin_amdgcn_mfma_f32_16x16x32_bf16(ad[mt], WcB[nt], pacc[nt][mt], 0, 0, 0);
      {
        float* fs = featacc + (t & 3) * FACC_ELE;
#pragma unroll
        for (int nt = 0; nt < 4; ++nt) {
          int c = (wv * 4 + nt) * 16 + (ln & 15);
          int cb = (c >> 5) * 2048 + ((c & 31) >> 3) * 128 + (c & 7);
#pragma unroll
          for (int mt = 0; mt < 4; ++mt)
#pragma unroll
            for (int reg = 0; reg < 4; ++reg)
              atadd(fs + cb + mt * 512 + ((ln >> 4) * 4 + reg) * 8, pacc[nt][mt][reg]);
        }
      }
      VMCNT0();
      __syncthreads();
      if (tid == 0) {
        setflag(&dflag[dw * 16], (u32)(t + 1));
        (void)__hip_atomic_fetch_add(&fcnt[(t & 3) * 16], 1u,
                                     __ATOMIC_RELAXED, __HIP_MEMORY_SCOPE_AGENT);
      }
      r = rn; rn = (rn == 2) ? 0 : rn + 1;
    }
  } else {
    // ===== lazy y WG (off the recurrence): y = d @ W_out^T + b_out =====
    float* red = (float*)smem;                 // [4 wv][16 tile][64][4] = 64KB
    const int c15 = ln & 15, qq = ln >> 4;
    short8 WoR[2][4];
#pragma unroll
    for (int kk = 0; kk < 2; ++kk) {
      int koffo = (wv * 2 + kk) * 32 + qq * 8;
#pragma unroll
      for (int nt = 0; nt < 4; ++nt)
        WoR[kk][nt] = cvt8(W_out + (nt * 16 + c15) * 256 + koffo);
    }
    float bout_r = b_out[wv * 16 + c15];
    for (int t = 0; t < SEQ; ++t) {
      if (tid < 8) pollge(&dflag[tid * 16], (u32)(t + 1));
      __syncthreads();
      const u16* dbufR = dbase + (t & 1) * D_ELE;
      short8 da[2][4];
#pragma unroll
      for (int kk = 0; kk < 2; ++kk)
#pragma unroll
        for (int mt = 0; mt < 4; ++mt)
          da[kk][mt] = ldc16(dbufR + (((wv * 2 + kk) * 4 + mt) * 64 + ln) * 8);
      f32x4 acc[4][4];
#pragma unroll
      for (int nt = 0; nt < 4; nt++)
#pragma unroll
        for (int mt = 0; mt < 4; mt++) acc[nt][mt] = (f32x4){0.f, 0.f, 0.f, 0.f};
#pragma unroll
      for (int kk = 0; kk < 2; ++kk)
#pragma unroll
        for (int nt = 0; nt < 4; nt++)
#pragma unroll
          for (int mt = 0; mt < 4; mt++)
            acc[nt][mt] = __builtin_amdgcn_mfma_f32_16x16x32_bf16(da[kk][mt], WoR[kk][nt], acc[nt][mt], 0, 0, 0);
#pragma unroll
      for (int nt = 0; nt < 4; nt++)
#pragma unroll
        for (int mt = 0; mt < 4; mt++)
          *(f32x4*)(red + ((wv * 16 + nt * 4 + mt) * 64 + ln) * 4) = acc[nt][mt];
      __syncthreads();
#pragma unroll
      for (int mt = 0; mt < 4; ++mt) {
        f32x4 s = (f32x4){0.f, 0.f, 0.f, 0.f};
#pragma unroll
        for (int w2 = 0; w2 < 4; ++w2)
          s += *(const f32x4*)(red + ((w2 * 16 + wv * 4 + mt) * 64 + ln) * 4);
#pragma unroll
        for (int r2 = 0; r2 < 4; ++r2) {
          int row = mt * 16 + qq * 4 + r2;
          out[t * 4096 + row * 64 + wv * 16 + c15] = s[r2] + bout_r;
        }
      }
      __syncthreads();
    }
  }
}

extern "C" void kernel_launch(void* const* d_in, const int* in_sizes, int n_in,
                              void* d_out, int out_size, void* d_ws, size_t ws_size,
                              hipStream_t stream) {
  const float* x     = (const float*)d_in[0];
  const float* msel  = (const float*)d_in[1];
  const float* W_fx  = (const float*)d_in[2];
  const float* b_fx  = (const float*)d_in[3];
  const float* W_ih  = (const float*)d_in[4];
  const float* W_hh  = (const float*)d_in[5];
  const float* b_ih  = (const float*)d_in[6];
  const float* b_hh  = (const float*)d_in[7];
  const float* W_hx  = (const float*)d_in[8];
  const float* b_hx  = (const float*)d_in[9];
  const float* W_out = (const float*)d_in[10];
  const float* b_out = (const float*)d_in[11];

  uint8_t* ws = (uint8_t*)d_ws;
  u16*   Abase   = (u16*)ws;                  // ring of 3 x 98304 B
  u16*   dbase   = (u16*)(ws + 294912);       // ring of 2 x 32768 B
  u32*   flags   = (u32*)(ws + 360448);       // 6144 B (u32[1536])
  float* featacc = (float*)(ws + 368640);     // 4 x 65536 B
  float* bcomb   = (float*)(ws + 630784);     // 1024 B
  u16*   Wcpack  = (u16*)(ws + 631808);       // 131072 B
  u16*   ftf     = (u16*)(ws + 762880);       // 256 x 32768 B = 8 MB

  prep_misc<<<23, 256, 0, stream>>>(W_fx, b_fx, W_out, b_out,
                                    Abase, flags, featacc, bcomb, Wcpack);
  prep_ftf<<<256, 256, 0, stream>>>(x, W_fx, b_fx, ftf);
  rnn_kernel<<<NWG, 256, 0, stream>>>(x, msel, W_ih, W_hh, b_ih, b_hh,
                                      W_hx, b_hx, W_out, b_out,
                                      (float*)d_out, Abase, dbase, flags,
                                      featacc, bcomb, Wcpack, ftf);
}